// Round 4
// baseline (89.752 us; speedup 1.0000x reference)
//
#include <hip/hip_runtime.h>

#ifndef __has_builtin
#define __has_builtin(x) 0
#endif

__device__ __forceinline__ float fexp2(float v) {
#if __has_builtin(__builtin_amdgcn_exp2f)
    return __builtin_amdgcn_exp2f(v);   // raw v_exp_f32
#else
    return exp2f(v);
#endif
}
__device__ __forceinline__ float frcp(float v) {
#if __has_builtin(__builtin_amdgcn_rcpf)
    return __builtin_amdgcn_rcpf(v);    // raw v_rcp_f32 (~1 ulp; threshold 1.5e-2)
#else
    return 1.0f / v;
#endif
}

// Problem constants: B, CIN, H, W = 8, 1, 192, 192; COUT, KH, KW = 8, 7, 7
constexpr int B_    = 8;
constexpr int H_    = 192;
constexpr int W_    = 192;
constexpr int COUT_ = 8;
constexpr int KH_   = 7;
constexpr int KW_   = 7;
constexpr int HO_   = H_ - KH_ + 1;  // 186
constexpr int WO_   = W_ - KW_ + 1;  // 186
constexpr float LOG2E = 1.44269504088896340736f;

constexpr int TX   = 64;             // output tile x per block
constexpr int TY   = 16;             // output tile y per block (R2 was 32: too big)
constexpr int IX   = TX + KW_ - 1;   // 70 input cols staged
constexpr int IY   = TY + KH_ - 1;   // 22 input rows staged
constexpr int NPIX = IX * IY;        // 1540
constexpr int NSLOT = (NPIX + 255) / 256;  // 7 staging slots (last: 4 threads)

// ws table: per (c,ky) one 16-float row: [F0..F6, 0, G0..G6, 0]
// F = exp(a*f) (as exp2 of a*log2e*f), G = F*f. One s_load_dwordx16 per row.
__global__ void smorph_setup(const float* __restrict__ filt,
                             const float* __restrict__ alpha,
                             float* __restrict__ ws) {
    int i = threadIdx.x;                 // 64 threads, 56 active
    if (i < COUT_ * KH_) {
        int c = i / 7, ky = i - c * 7;
        float a2 = alpha[c] * LOG2E;
        float* t = ws + (c * 7 + ky) * 16;
#pragma unroll
        for (int kx = 0; kx < 7; ++kx) {
            float f = filt[(c * 7 + ky) * 7 + kx];
            float F = fexp2(a2 * f);
            t[kx]     = F;
            t[8 + kx] = F * f;
        }
        t[7] = 0.f; t[15] = 0.f;
    }
}

// exp(a(x+f)) = P * F_k with P = exp2(a2*x).  H = x*P.
// num = sum_k (F_k*H + G_k*P); den = sum_k F_k*P; out = num/den.
//
// CHANGE vs R2 (tile 64x32, 8 out/thread, 1152 blocks, VGPR 128): that
// config was latency-bound (Occ 18%, VALUBusy 26%, 4.5 blocks/CU of work
// vs a 4-block VGPR cap). Interpolate back: tile 64x16, 4 outputs/thread
// (2x*2y), grid (3,12,64)=2304 blocks (9 blocks/CU of work), LDS 12.3 KB,
// target VGPR ~96 (5 waves/SIMD resident). LDS stays 8 b128-reads/output.
__global__ __launch_bounds__(256) void smorph_main(
    const float* __restrict__ x,      // (B,1,H,W)
    const float* __restrict__ alpha,  // (COUT,1)
    const float* __restrict__ fg,     // setup table
    float* __restrict__ out)          // (B,COUT,HO,WO)
{
    __shared__ __align__(16) float2 PH[IY * IX];   // 12320 B

    const int tx  = threadIdx.x;      // 0..31
    const int ty  = threadIdx.y;      // 0..7
    const int tid = ty * 32 + tx;
    const int bx0 = blockIdx.x * TX;
    const int by0 = blockIdx.y * TY;
    const int z   = blockIdx.z;       // b*COUT + c
    const int c   = z & 7;
    const float* xb = x + (z >> 3) * (H_ * W_);
    const float a2  = alpha[c] * LOG2E;   // uniform -> s_load

    // Phase 1: stage P,H. 7 slots/thread (last slot: 4 threads active).
#pragma unroll
    for (int s = 0; s < NSLOT; ++s) {
        const int i = tid + 256 * s;
        if (i < NPIX) {
            const int iy = i / IX, ix = i - iy * IX;
            // Clamped coords only feed rows/cols >= H/W which only reach
            // outputs >= HO/WO (masked at store).
            const float xv = xb[min(by0 + iy, H_ - 1) * W_ + min(bx0 + ix, W_ - 1)];
            const float P = fexp2(a2 * xv);
            PH[i] = make_float2(P, xv * P);
        }
    }
    __syncthreads();   // the only barrier in the kernel

    // Phase 2: 7x7 correlation, 4 outputs/thread (2 in x, 2 in y).
    const int ox  = bx0 + 2 * tx;
    const int oyb = by0 + 2 * ty;
    const bool vx = (ox + 1 < WO_);   // ox even: both-or-neither in x

    float num[2][2] = {};
    float den[2][2] = {};
    const float* tc = fg + c * (7 * 16);

    // Each staged input row ir (of 8) is read ONCE and feeds output rows
    // ro in {ir-6..ir} ∩ {0,1}. F/G come from scalar cache (uniform).
#pragma unroll
    for (int ir = 0; ir < 2 + KH_ - 1; ++ir) {        // 8 input rows
        const float4* rp = (const float4*)&PH[(2 * ty + ir) * IX + 2 * tx];
        float4 q0 = rp[0], q1 = rp[1], q2 = rp[2], q3 = rp[3];
        float P[8]  = {q0.x, q0.z, q1.x, q1.z, q2.x, q2.z, q3.x, q3.z};
        float Hh[8] = {q0.y, q0.w, q1.y, q1.w, q2.y, q2.w, q3.y, q3.w};
#pragma unroll
        for (int ro = 0; ro < 2; ++ro) {
            const int ky = ir - ro;
            if (ky < 0 || ky > KH_ - 1) continue;
            const float* t = tc + ky * 16;   // uniform -> s_load_dwordx16
#pragma unroll
            for (int kx = 0; kx < 7; ++kx) {
                const float F = t[kx], G = t[8 + kx];
                num[ro][0] = fmaf(F, Hh[kx],     num[ro][0]);
                num[ro][0] = fmaf(G, P[kx],      num[ro][0]);
                den[ro][0] = fmaf(F, P[kx],      den[ro][0]);
                num[ro][1] = fmaf(F, Hh[kx + 1], num[ro][1]);
                num[ro][1] = fmaf(G, P[kx + 1],  num[ro][1]);
                den[ro][1] = fmaf(F, P[kx + 1],  den[ro][1]);
            }
        }
    }

#pragma unroll
    for (int ro = 0; ro < 2; ++ro) {
        const int oy = oyb + ro;
        if (vx && oy < HO_) {
            float2 o;
            o.x = num[ro][0] * frcp(den[ro][0]);
            o.y = num[ro][1] * frcp(den[ro][1]);
            *(float2*)&out[(z * HO_ + oy) * WO_ + ox] = o;
        }
    }
}

extern "C" void kernel_launch(void* const* d_in, const int* in_sizes, int n_in,
                              void* d_out, int out_size, void* d_ws, size_t ws_size,
                              hipStream_t stream) {
    const float* x     = (const float*)d_in[0];
    const float* filt  = (const float*)d_in[1];
    const float* alpha = (const float*)d_in[2];
    float* out = (float*)d_out;
    float* ws  = (float*)d_ws;

    smorph_setup<<<1, 64, 0, stream>>>(filt, alpha, ws);

    dim3 block(32, 8, 1);
    dim3 grid((WO_ + TX - 1) / TX, (HO_ + TY - 1) / TY, B_ * COUT_);  // (3, 12, 64)
    smorph_main<<<grid, block, 0, stream>>>(x, alpha, ws, out);
}

// Round 5
// 76.062 us; speedup vs baseline: 1.1800x; 1.1800x over previous
//
#include <hip/hip_runtime.h>

#ifndef __has_builtin
#define __has_builtin(x) 0
#endif

__device__ __forceinline__ float fexp2(float v) {
#if __has_builtin(__builtin_amdgcn_exp2f)
    return __builtin_amdgcn_exp2f(v);   // raw v_exp_f32
#else
    return exp2f(v);
#endif
}
__device__ __forceinline__ float frcp(float v) {
#if __has_builtin(__builtin_amdgcn_rcpf)
    return __builtin_amdgcn_rcpf(v);    // raw v_rcp_f32 (~1 ulp; threshold 1.5e-2)
#else
    return 1.0f / v;
#endif
}

// Problem constants: B, CIN, H, W = 8, 1, 192, 192; COUT, KH, KW = 8, 7, 7
constexpr int B_    = 8;
constexpr int H_    = 192;
constexpr int W_    = 192;
constexpr int COUT_ = 8;
constexpr int KH_   = 7;
constexpr int KW_   = 7;
constexpr int HO_   = H_ - KH_ + 1;  // 186
constexpr int WO_   = W_ - KW_ + 1;  // 186
constexpr float LOG2E = 1.44269504088896340736f;

// CHANGE vs R1-R4: the kernel is latency-bound, not pipe-bound (R3 clean
// counters: Occ 18%, VALUBusy 26%, HBM 3%; main time tracked 1/work-TLP
// across R0/R1/R3/R4 while ILP variants never paid off). So: maximize
// waves. 128-thread blocks (2-wave barrier groups), tile 32x8, grid
// (6,24,64) = 9216 blocks = 18 waves/SIMD of work, and __launch_bounds__
// (128,8) to cap VGPR at 64 -> 8 resident waves/SIMD. Per-thread shape
// stays R1's proven 2-outputs / 14 b128-reads.
constexpr int NTHR = 128;            // 2 waves per block
constexpr int TX   = 32;             // output tile x per block
constexpr int TY   = 8;              // output tile y per block
constexpr int IX   = TX + KW_ - 1;   // 38 input cols staged
constexpr int IY   = TY + KH_ - 1;   // 14 input rows staged
constexpr int NPIX = IX * IY;        // 532
constexpr int NSLOT = (NPIX + NTHR - 1) / NTHR;  // 5 (last slot: 20 threads)

// ws table: per (c,ky) one 16-float row: [F0..F6, 0, G0..G6, 0]
// F = exp(a*f) (as exp2 of a*log2e*f), G = F*f. One s_load_dwordx16 per row.
__global__ void smorph_setup(const float* __restrict__ filt,
                             const float* __restrict__ alpha,
                             float* __restrict__ ws) {
    int i = threadIdx.x;                 // 64 threads, 56 active
    if (i < COUT_ * KH_) {
        int c = i / 7, ky = i - c * 7;
        float a2 = alpha[c] * LOG2E;
        float* t = ws + (c * 7 + ky) * 16;
#pragma unroll
        for (int kx = 0; kx < 7; ++kx) {
            float f = filt[(c * 7 + ky) * 7 + kx];
            float F = fexp2(a2 * f);
            t[kx]     = F;
            t[8 + kx] = F * f;
        }
        t[7] = 0.f; t[15] = 0.f;
    }
}

// exp(a(x+f)) = P * F_k with P = exp2(a2*x).  H = x*P.
// num = sum_k (F_k*H + G_k*P); den = sum_k F_k*P; out = num/den.
__global__ __launch_bounds__(NTHR, 8) void smorph_main(
    const float* __restrict__ x,      // (B,1,H,W)
    const float* __restrict__ alpha,  // (COUT,1)
    const float* __restrict__ fg,     // setup table
    float* __restrict__ out)          // (B,COUT,HO,WO)
{
    __shared__ __align__(16) float2 PH[IY * IX];   // 4256 B

    const int tx  = threadIdx.x;      // 0..31
    const int ty  = threadIdx.y;      // 0..3
    const int tid = ty * 32 + tx;
    const int bx0 = blockIdx.x * TX;
    const int by0 = blockIdx.y * TY;
    const int z   = blockIdx.z;       // b*COUT + c
    const int c   = z & 7;
    const float* xb = x + (z >> 3) * (H_ * W_);
    const float a2  = alpha[c] * LOG2E;   // uniform -> s_load

    // Phase 1: stage P,H. 5 slots/thread (slots 0..3 full, slot 4: 20 thr).
#pragma unroll
    for (int s = 0; s < NSLOT; ++s) {
        const int i = tid + NTHR * s;
        if (i < NPIX) {
            const int iy = i / IX, ix = i - iy * IX;
            // Clamped coords only feed rows/cols >= H/W which only reach
            // outputs >= HO/WO (masked at store).
            const float xv = xb[min(by0 + iy, H_ - 1) * W_ + min(bx0 + ix, W_ - 1)];
            const float P = fexp2(a2 * xv);
            PH[i] = make_float2(P, xv * P);
        }
    }
    __syncthreads();   // 2-wave barrier (the only one)

    // Phase 2: 7x7 correlation, 2 outputs/thread (pair in x).
    // 16 x-slots * 8 y-rows = 128 threads.
    const int xs = tx & 15;
    const int yr = (ty << 1) | (tx >> 4);
    const int ox = bx0 + 2 * xs;
    const int oy = by0 + yr;
    const bool vx = (ox + 1 < WO_);   // ox even: both-or-neither in x

    float num0 = 0.f, den0 = 0.f, num1 = 0.f, den1 = 0.f;
    const float* tc = fg + c * (7 * 16);
#pragma unroll
    for (int ky = 0; ky < KH_; ++ky) {
        const float* t = tc + ky * 16;   // uniform -> s_load_dwordx16
        const float4* rp = (const float4*)&PH[(yr + ky) * IX + 2 * xs];
        float4 q0 = rp[0], q1 = rp[1], q2 = rp[2], q3 = rp[3];
        float P[8]  = {q0.x, q0.z, q1.x, q1.z, q2.x, q2.z, q3.x, q3.z};
        float Hh[8] = {q0.y, q0.w, q1.y, q1.w, q2.y, q2.w, q3.y, q3.w};
#pragma unroll
        for (int kx = 0; kx < 7; ++kx) {
            const float F = t[kx], G = t[8 + kx];
            num0 = fmaf(F, Hh[kx],     num0);
            num0 = fmaf(G, P[kx],      num0);
            den0 = fmaf(F, P[kx],      den0);
            num1 = fmaf(F, Hh[kx + 1], num1);
            num1 = fmaf(G, P[kx + 1],  num1);
            den1 = fmaf(F, P[kx + 1],  den1);
        }
    }

    if (vx && oy < HO_) {
        float2 o;
        o.x = num0 * frcp(den0);
        o.y = num1 * frcp(den1);
        *(float2*)&out[(z * HO_ + oy) * WO_ + ox] = o;
    }
}

extern "C" void kernel_launch(void* const* d_in, const int* in_sizes, int n_in,
                              void* d_out, int out_size, void* d_ws, size_t ws_size,
                              hipStream_t stream) {
    const float* x     = (const float*)d_in[0];
    const float* filt  = (const float*)d_in[1];
    const float* alpha = (const float*)d_in[2];
    float* out = (float*)d_out;
    float* ws  = (float*)d_ws;

    smorph_setup<<<1, 64, 0, stream>>>(filt, alpha, ws);

    dim3 block(32, 4, 1);
    dim3 grid((WO_ + TX - 1) / TX, (HO_ + TY - 1) / TY, B_ * COUT_);  // (6, 24, 64)
    smorph_main<<<grid, block, 0, stream>>>(x, alpha, ws, out);
}